// Round 6
// baseline (181.664 us; speedup 1.0000x reference)
//
#include <hip/hip_runtime.h>
#include <hip/hip_bf16.h>

typedef float f32x4 __attribute__((ext_vector_type(4)));
typedef short bf16x8 __attribute__((ext_vector_type(8)));

#define B_DIM 4096
#define C_DIM 1000
#define CP 1024
#define K1 2048
#define EPS 1e-6f

__device__ __forceinline__ float wsum(float v) {
#pragma unroll
  for (int o = 32; o > 0; o >>= 1) v += __shfl_xor(v, o, 64);
  return v;
}
__device__ __forceinline__ float wmax(float v) {
#pragma unroll
  for (int o = 32; o > 0; o >>= 1) v = fmaxf(v, __shfl_xor(v, o, 64));
  return v;
}

__device__ __forceinline__ void load_lds16(const void* g, void* l) {
  __builtin_amdgcn_global_load_lds(
      (const __attribute__((address_space(1))) unsigned int*)g,
      (__attribute__((address_space(3))) unsigned int*)l, 16, 0, 0);
}

// ---- merged prep: blocks [0,CP) = per-class, [CP, CP+B_DIM) = per-b ----
__global__ void prep_all(const float* __restrict__ sig,
                         const float* __restrict__ lr,
                         const float* __restrict__ pe,
                         __hip_bfloat16* __restrict__ wsig,
                         float* __restrict__ expd,
                         __hip_bfloat16* __restrict__ elc,
                         __hip_bfloat16* __restrict__ pen,
                         float* __restrict__ ssb,
                         __hip_bfloat16* __restrict__ elb) {
  const int t = threadIdx.x;
  if (blockIdx.x < CP) {
    const int c = blockIdx.x;
    if (c >= C_DIM) {  // zero padding rows so the GEMM reads clean zeros
      for (int i = t; i < K1; i += 64) wsig[(size_t)c * K1 + i] = __float2bfloat16(0.f);
      if (t < 32) expd[c * 32 + t] = 0.f;
      elc[(size_t)c * 128 + t] = __float2bfloat16(0.f);
      elc[(size_t)c * 128 + 64 + t] = __float2bfloat16(0.f);
      return;
    }
    float lv = (t < 32) ? lr[c * 32 + t] : -3.0e38f;
    float mx = wmax(lv);
    float ev = (t < 32) ? expf(lv - mx) : 0.f;
    float sden = wsum(ev);
    float res = ev / sden;
    if (t < 31) {
      float d = lr[c * 32 + t] - lr[c * 32 + t + 1];
      expd[c * 32 + t] = 1.f / (1.f + expf(-d));
    } else if (t == 31) {
      expd[c * 32 + 31] = 0.f;
    }
    float es = 0.f, ls = 0.f;
    for (int l = 0; l < 32; ++l) {
      float s = sig[((size_t)c * 32 + l) * 64 + t];
      float nrm = fmaxf(sqrtf(wsum(s * s)), 1e-12f);
      float resl = __shfl(res, l, 64);
      wsig[((size_t)c * 32 + l) * 64 + t] = __float2bfloat16(s / nrm * resl);
      if (l < 16) es += s; else ls += s;
    }
    es *= (1.f / 16.f); ls *= (1.f / 16.f);
    float en = fmaxf(sqrtf(wsum(es * es)), 1e-12f);
    float ln2 = fmaxf(sqrtf(wsum(ls * ls)), 1e-12f);
    elc[(size_t)c * 128 + t] = __float2bfloat16(es / en);
    elc[(size_t)c * 128 + 64 + t] = __float2bfloat16(ls / ln2);
  } else {
    const int b = blockIdx.x - CP;
    float v[32];
#pragma unroll
    for (int l = 0; l < 32; ++l) v[l] = pe[((size_t)b * 32 + l) * 64 + t];
    float nrm[32];
#pragma unroll
    for (int l = 0; l < 32; ++l) nrm[l] = sqrtf(wsum(v[l] * v[l]));
#pragma unroll
    for (int l = 0; l < 32; ++l)
      pen[((size_t)b * 32 + l) * 64 + t] = __float2bfloat16(v[l] / fmaxf(nrm[l], 1e-12f));
#pragma unroll
    for (int l = 0; l < 31; ++l) {
      float dot = wsum(v[l] * v[l + 1]);
      float cosv = dot / (fmaxf(nrm[l], 1e-8f) * fmaxf(nrm[l + 1], 1e-8f));
      if (t == 0) ssb[(size_t)b * 32 + l] = (cosv + 1.0f) * 0.5f;
    }
    if (t == 0) ssb[(size_t)b * 32 + 31] = 0.0f;
    float es = 0.f, ls = 0.f;
#pragma unroll
    for (int l = 0; l < 16; ++l) es += v[l];
#pragma unroll
    for (int l = 16; l < 32; ++l) ls += v[l];
    es *= (1.f / 16.f); ls *= (1.f / 16.f);
    float en = fmaxf(sqrtf(wsum(es * es)), 1e-12f);
    float ln2 = fmaxf(sqrtf(wsum(ls * ls)), 1e-12f);
    elb[(size_t)b * 128 + t] = __float2bfloat16(es / en);
    elb[(size_t)b * 128 + 64 + t] = __float2bfloat16(ls / ln2);
  }
}

// ---- main fused: 128x64 tile, 8 waves (32x32 each), BK=64, 3-deep vmcnt ----
__global__ __launch_bounds__(512, 4)
void basin_main(const __hip_bfloat16* __restrict__ pen,
                const __hip_bfloat16* __restrict__ wsig,
                const __hip_bfloat16* __restrict__ elb,
                const __hip_bfloat16* __restrict__ elc,
                const float* __restrict__ ssb,
                const float* __restrict__ expd,
                const float* __restrict__ cm,
                const float* __restrict__ proto,
                float* __restrict__ out) {
  __shared__ __align__(16) char smem[73728];  // 3 x (A 16KB + B 8KB)
  const int t = threadIdx.x;
  const int lane = t & 63;
  const int w = t >> 6;                // 0..7
  const int wm = w >> 1, wn = w & 1;   // 4M x 2N waves, each 32x32
  // XCD-chunk swizzle: 8 chunks (4 row-chunks x 2 col-chunks) of 8x8 tiles.
  const int wg = blockIdx.x;           // 0..511; dispatcher: xcd = wg & 7
  const int xcd = wg & 7, ii = wg >> 3;
  const int brow = (((xcd >> 1) << 3) + (ii >> 3)) * 128;
  const int bcol = (((xcd & 1) << 3) + (ii & 7)) * 64;
  // staging: 8 threads per 128B row; granule-XOR swizzle (both sides, row&7)
  const int srow = t >> 3;                       // 0..63
  const int selem = (((t & 7) ^ (srow & 7)) << 3);  // pre-swizzled source elem
  const int l15 = lane & 15;
  const int gq = lane >> 4;                      // quarter 0..3

  f32x4 acc1[2][2] = {};
  f32x4 acc2[2][2] = {};

#define BUFA(bi) (smem + (bi) * 24576)
#define BUFB(bi) (smem + (bi) * 24576 + 16384)

#define STAGE_T(kt, bi)                                                                     \
  do {                                                                                      \
    load_lds16(pen + (size_t)(brow + srow) * K1 + (kt) * 64 + selem, BUFA(bi) + t * 16);    \
    load_lds16(pen + (size_t)(brow + 64 + srow) * K1 + (kt) * 64 + selem,                   \
               BUFA(bi) + 8192 + t * 16);                                                   \
    load_lds16(wsig + (size_t)(bcol + srow) * K1 + (kt) * 64 + selem, BUFB(bi) + t * 16);   \
  } while (0)

#define STAGE_H(kt, bi)                                                                     \
  do {                                                                                      \
    load_lds16(elb + (size_t)(brow + srow) * 128 + (kt) * 64 + selem, BUFA(bi) + t * 16);   \
    load_lds16(elb + (size_t)(brow + 64 + srow) * 128 + (kt) * 64 + selem,                  \
               BUFA(bi) + 8192 + t * 16);                                                   \
    load_lds16(elc + (size_t)(bcol + srow) * 128 + (kt) * 64 + selem, BUFB(bi) + t * 16);   \
  } while (0)

// per K-step: 2 sub-steps (kk), 8 ds_read_b128, 8 MFMA
#define COMPUTE(ACC, bi)                                                                    \
  do {                                                                                      \
    _Pragma("unroll") for (int kk = 0; kk < 2; ++kk) {                                      \
      bf16x8 af[2], bg[2];                                                                  \
      _Pragma("unroll") for (int m = 0; m < 2; ++m) {                                       \
        int row = wm * 32 + m * 16 + l15;                                                   \
        int g = kk * 4 + gq;                                                                \
        af[m] = *(const bf16x8*)(BUFA(bi) + row * 128 + ((g ^ (row & 7)) << 4));            \
      }                                                                                     \
      _Pragma("unroll") for (int n = 0; n < 2; ++n) {                                       \
        int row = wn * 32 + n * 16 + l15;                                                   \
        int g = kk * 4 + gq;                                                                \
        bg[n] = *(const bf16x8*)(BUFB(bi) + row * 128 + ((g ^ (row & 7)) << 4));            \
      }                                                                                     \
      _Pragma("unroll") for (int m = 0; m < 2; ++m)                                         \
        _Pragma("unroll") for (int n = 0; n < 2; ++n)                                       \
          ACC[m][n] = __builtin_amdgcn_mfma_f32_16x16x32_bf16(af[m], bg[n], ACC[m][n], 0, 0, 0); \
    }                                                                                       \
  } while (0)

  // ---- triadic GEMM: K=2048, 32 steps of BK=64, 3-buffer counted-vmcnt ----
  int i0 = 0, i1 = 1, i2 = 2;
  STAGE_T(0, 0);
  STAGE_T(1, 1);
  for (int kt = 0; kt < 32; ++kt) {
    if (kt < 31) {
      asm volatile("s_waitcnt vmcnt(3)" ::: "memory");  // stage(kt) landed; stage(kt+1) in flight
    } else {
      asm volatile("s_waitcnt vmcnt(0)" ::: "memory");
    }
    __builtin_amdgcn_s_barrier();
    __builtin_amdgcn_sched_barrier(0);
    if (kt < 30) STAGE_T(kt + 2, i2);
    COMPUTE(acc1, i0);
    int tmp = i0; i0 = i1; i1 = i2; i2 = tmp;
  }
  __syncthreads();  // all waves done reading before buffer reuse

  // ---- hier GEMM: K=128 = 2 steps; both staged, one drain ----
  STAGE_H(0, 0);
  STAGE_H(1, 1);
  __syncthreads();  // compiler drains vmcnt before barrier
  COMPUTE(acc2, 0);
  COMPUTE(acc2, 1);
  __syncthreads();  // done reading before epilogue overwrites smem

  // ---- epilogue: stage ss/exp rows + cantor scalars in LDS ----
  float* ss_l = (float*)smem;            // [128][36] padded stride
  float* ex_l = (float*)(smem + 18432);  // [64][36]
  float* cm_l = (float*)(smem + 27648);  // [128]
  float* pr_l = (float*)(smem + 28160);  // [64]
  for (int i = t; i < 4096; i += 512) {
    int r = i >> 5, l = i & 31;
    ss_l[r * 36 + l] = ssb[(size_t)(brow + r) * 32 + l];
  }
  for (int i = t; i < 2048; i += 512) {
    int r = i >> 5, l = i & 31;
    ex_l[r * 36 + l] = expd[(size_t)(bcol + r) * 32 + l];
  }
  if (t < 128) cm_l[t] = cm[brow + t];
  if (t < 64) pr_l[t] = (bcol + t < C_DIM) ? proto[bcol + t] : 0.f;
  __syncthreads();

  const int col0 = wn * 32 + l15;
  const int row0 = wm * 32 + (gq << 2);
#pragma unroll
  for (int m = 0; m < 2; ++m) {
    float ssum[4][2];
#pragma unroll
    for (int j = 0; j < 4; ++j)
#pragma unroll
      for (int n = 0; n < 2; ++n) ssum[j][n] = 0.f;
#pragma unroll
    for (int l4 = 0; l4 < 32; l4 += 4) {
      f32x4 evv[2], sv[4];
#pragma unroll
      for (int n = 0; n < 2; ++n)
        evv[n] = *(const f32x4*)&ex_l[(col0 + n * 16) * 36 + l4];
#pragma unroll
      for (int j = 0; j < 4; ++j)
        sv[j] = *(const f32x4*)&ss_l[(row0 + m * 16 + j) * 36 + l4];
#pragma unroll
      for (int j = 0; j < 4; ++j)
#pragma unroll
        for (int n = 0; n < 2; ++n) {
          ssum[j][n] += fabsf(sv[j][0] - evv[n][0]) + fabsf(sv[j][1] - evv[n][1]) +
                        fabsf(sv[j][2] - evv[n][2]) + fabsf(sv[j][3] - evv[n][3]);
        }
    }
#pragma unroll
    for (int j = 0; j < 4; ++j) {
      int rloc = row0 + m * 16 + j;
      float cmv = cm_l[rloc];
#pragma unroll
      for (int n = 0; n < 2; ++n) {
        int cloc = col0 + n * 16;
        int cg = bcol + cloc;
        float tria = fminf(fmaxf(0.5f + 0.5f * acc1[m][n][j], EPS), 1.0f);
        float hier = fminf(fmaxf(0.5f + 0.25f * acc2[m][n][j], EPS), 1.0f);
        float sc = fminf(fmaxf(1.0f - ssum[j][n] * (1.0f / 31.0f), EPS), 1.0f);
        float d = cmv - pr_l[cloc];
        float cc = __expf(d * d * -10.0f) + 1e-8f;
        cc = fminf(fmaxf(cc, EPS), 1.0f);
        float p = tria * sc * cc * hier;
        if (cg < C_DIM)
          out[(size_t)(brow + rloc) * C_DIM + cg] = sqrtf(sqrtf(p));
      }
    }
  }
}

extern "C" void kernel_launch(void* const* d_in, const int* in_sizes, int n_in,
                              void* d_out, int out_size, void* d_ws, size_t ws_size,
                              hipStream_t stream) {
  (void)in_sizes; (void)n_in; (void)out_size; (void)ws_size;
  const float* pe = (const float*)d_in[0];     // B x L x F
  const float* cm = (const float*)d_in[1];     // B
  const float* sig = (const float*)d_in[2];    // C x L x F
  const float* proto = (const float*)d_in[3];  // C
  const float* lr = (const float*)d_in[4];     // C x L
  float* out = (float*)d_out;
  char* ws = (char*)d_ws;

  __hip_bfloat16* wsig = (__hip_bfloat16*)(ws);               // CP*2048*2 = 4 MiB
  __hip_bfloat16* pen = (__hip_bfloat16*)(ws + 4194304);      // B*2048*2 = 16 MiB
  __hip_bfloat16* elb = (__hip_bfloat16*)(ws + 20971520);     // B*128*2  = 1 MiB
  __hip_bfloat16* elc = (__hip_bfloat16*)(ws + 22020096);     // CP*128*2 = 256 KiB
  float* ssb = (float*)(ws + 22282240);                       // B*32*4   = 512 KiB
  float* expd = (float*)(ws + 22806528);                      // CP*32*4  = 128 KiB

  prep_all<<<CP + B_DIM, 64, 0, stream>>>(sig, lr, pe, wsig, expd, elc, pen, ssb, elb);
  basin_main<<<512, 512, 0, stream>>>(pen, wsig, elb, elc, ssb, expd, cm, proto, out);
}

// Round 7
// 173.752 us; speedup vs baseline: 1.0455x; 1.0455x over previous
//
#include <hip/hip_runtime.h>
#include <hip/hip_bf16.h>

typedef float f32x4 __attribute__((ext_vector_type(4)));
typedef short bf16x8 __attribute__((ext_vector_type(8)));

#define B_DIM 4096
#define C_DIM 1000
#define CP 1024
#define K1 2048
#define EPS 1e-6f

__device__ __forceinline__ float wsum(float v) {
#pragma unroll
  for (int o = 32; o > 0; o >>= 1) v += __shfl_xor(v, o, 64);
  return v;
}
__device__ __forceinline__ float wmax(float v) {
#pragma unroll
  for (int o = 32; o > 0; o >>= 1) v = fmaxf(v, __shfl_xor(v, o, 64));
  return v;
}

__device__ __forceinline__ void load_lds16(const void* g, void* l) {
  __builtin_amdgcn_global_load_lds(
      (const __attribute__((address_space(1))) unsigned int*)g,
      (__attribute__((address_space(3))) unsigned int*)l, 16, 0, 0);
}

// ---- merged prep: blocks [0,CP) = per-class, [CP, CP+B_DIM) = per-b ----
__global__ void prep_all(const float* __restrict__ sig,
                         const float* __restrict__ lr,
                         const float* __restrict__ pe,
                         __hip_bfloat16* __restrict__ wsig,
                         float* __restrict__ expd,
                         __hip_bfloat16* __restrict__ elc,
                         __hip_bfloat16* __restrict__ pen,
                         float* __restrict__ ssb,
                         __hip_bfloat16* __restrict__ elb) {
  const int t = threadIdx.x;
  if (blockIdx.x < CP) {
    const int c = blockIdx.x;
    if (c >= C_DIM) {  // zero padding rows so the GEMM reads clean zeros
      for (int i = t; i < K1; i += 64) wsig[(size_t)c * K1 + i] = __float2bfloat16(0.f);
      if (t < 32) expd[c * 32 + t] = 0.f;
      elc[(size_t)c * 128 + t] = __float2bfloat16(0.f);
      elc[(size_t)c * 128 + 64 + t] = __float2bfloat16(0.f);
      return;
    }
    float lv = (t < 32) ? lr[c * 32 + t] : -3.0e38f;
    float mx = wmax(lv);
    float ev = (t < 32) ? expf(lv - mx) : 0.f;
    float sden = wsum(ev);
    float res = ev / sden;
    if (t < 31) {
      float d = lr[c * 32 + t] - lr[c * 32 + t + 1];
      expd[c * 32 + t] = 1.f / (1.f + expf(-d));
    } else if (t == 31) {
      expd[c * 32 + 31] = 0.f;
    }
    float es = 0.f, ls = 0.f;
    for (int l = 0; l < 32; ++l) {
      float s = sig[((size_t)c * 32 + l) * 64 + t];
      float nrm = fmaxf(sqrtf(wsum(s * s)), 1e-12f);
      float resl = __shfl(res, l, 64);
      wsig[((size_t)c * 32 + l) * 64 + t] = __float2bfloat16(s / nrm * resl);
      if (l < 16) es += s; else ls += s;
    }
    es *= (1.f / 16.f); ls *= (1.f / 16.f);
    float en = fmaxf(sqrtf(wsum(es * es)), 1e-12f);
    float ln2 = fmaxf(sqrtf(wsum(ls * ls)), 1e-12f);
    elc[(size_t)c * 128 + t] = __float2bfloat16(es / en);
    elc[(size_t)c * 128 + 64 + t] = __float2bfloat16(ls / ln2);
  } else {
    const int b = blockIdx.x - CP;
    float v[32];
#pragma unroll
    for (int l = 0; l < 32; ++l) v[l] = pe[((size_t)b * 32 + l) * 64 + t];
    float nrm[32];
#pragma unroll
    for (int l = 0; l < 32; ++l) nrm[l] = sqrtf(wsum(v[l] * v[l]));
#pragma unroll
    for (int l = 0; l < 32; ++l)
      pen[((size_t)b * 32 + l) * 64 + t] = __float2bfloat16(v[l] / fmaxf(nrm[l], 1e-12f));
#pragma unroll
    for (int l = 0; l < 31; ++l) {
      float dot = wsum(v[l] * v[l + 1]);
      float cosv = dot / (fmaxf(nrm[l], 1e-8f) * fmaxf(nrm[l + 1], 1e-8f));
      if (t == 0) ssb[(size_t)b * 32 + l] = (cosv + 1.0f) * 0.5f;
    }
    if (t == 0) ssb[(size_t)b * 32 + 31] = 0.0f;
    float es = 0.f, ls = 0.f;
#pragma unroll
    for (int l = 0; l < 16; ++l) es += v[l];
#pragma unroll
    for (int l = 16; l < 32; ++l) ls += v[l];
    es *= (1.f / 16.f); ls *= (1.f / 16.f);
    float en = fmaxf(sqrtf(wsum(es * es)), 1e-12f);
    float ln2 = fmaxf(sqrtf(wsum(ls * ls)), 1e-12f);
    elb[(size_t)b * 128 + t] = __float2bfloat16(es / en);
    elb[(size_t)b * 128 + 64 + t] = __float2bfloat16(ls / ln2);
  }
}

// ---- main fused: 128x64 tile, 8 waves (32x32 each), BK=64, 3-deep vmcnt ----
// Natural dispatch order (grid x = row-tile, fastest): 32 consecutive blocks
// share one wsig panel -> L2/L3 friendly (R5: FETCH 33MB). XCD-chunk swizzle
// REGRESSED 8x fetch/write (R6) -- mapping assumption invalid; do not re-add.
__global__ __launch_bounds__(512, 4)
void basin_main(const __hip_bfloat16* __restrict__ pen,
                const __hip_bfloat16* __restrict__ wsig,
                const __hip_bfloat16* __restrict__ elb,
                const __hip_bfloat16* __restrict__ elc,
                const float* __restrict__ ssb,
                const float* __restrict__ expd,
                const float* __restrict__ cm,
                const float* __restrict__ proto,
                float* __restrict__ out) {
  __shared__ __align__(16) char smem[73728];  // 3 x (A 16KB + B 8KB)
  const int t = threadIdx.x;
  const int lane = t & 63;
  const int w = t >> 6;                // 0..7
  const int wm = w >> 1, wn = w & 1;   // 4M x 2N waves, each 32x32
  const int brow = blockIdx.x * 128;
  const int bcol = blockIdx.y * 64;
  // staging: 8 threads per 128B row; granule-XOR swizzle (both sides, row&7)
  const int srow = t >> 3;                          // 0..63
  const int selem = (((t & 7) ^ (srow & 7)) << 3);  // pre-swizzled source elem
  const int l15 = lane & 15;
  const int gq = lane >> 4;                         // quarter 0..3

  f32x4 acc1[2][2] = {};
  f32x4 acc2[2][2] = {};

#define BUFA(bi) (smem + (bi) * 24576)
#define BUFB(bi) (smem + (bi) * 24576 + 16384)

#define STAGE_T(kt, bi)                                                                     \
  do {                                                                                      \
    load_lds16(pen + (size_t)(brow + srow) * K1 + (kt) * 64 + selem, BUFA(bi) + t * 16);    \
    load_lds16(pen + (size_t)(brow + 64 + srow) * K1 + (kt) * 64 + selem,                   \
               BUFA(bi) + 8192 + t * 16);                                                   \
    load_lds16(wsig + (size_t)(bcol + srow) * K1 + (kt) * 64 + selem, BUFB(bi) + t * 16);   \
  } while (0)

#define STAGE_H(kt, bi)                                                                     \
  do {                                                                                      \
    load_lds16(elb + (size_t)(brow + srow) * 128 + (kt) * 64 + selem, BUFA(bi) + t * 16);   \
    load_lds16(elb + (size_t)(brow + 64 + srow) * 128 + (kt) * 64 + selem,                  \
               BUFA(bi) + 8192 + t * 16);                                                   \
    load_lds16(elc + (size_t)(bcol + srow) * 128 + (kt) * 64 + selem, BUFB(bi) + t * 16);   \
  } while (0)

// per K-step: 2 sub-steps (kk), 8 ds_read_b128, 8 MFMA
#define COMPUTE(ACC, bi)                                                                    \
  do {                                                                                      \
    _Pragma("unroll") for (int kk = 0; kk < 2; ++kk) {                                      \
      bf16x8 af[2], bg[2];                                                                  \
      _Pragma("unroll") for (int m = 0; m < 2; ++m) {                                       \
        int row = wm * 32 + m * 16 + l15;                                                   \
        int g = kk * 4 + gq;                                                                \
        af[m] = *(const bf16x8*)(BUFA(bi) + row * 128 + ((g ^ (row & 7)) << 4));            \
      }                                                                                     \
      _Pragma("unroll") for (int n = 0; n < 2; ++n) {                                       \
        int row = wn * 32 + n * 16 + l15;                                                   \
        int g = kk * 4 + gq;                                                                \
        bg[n] = *(const bf16x8*)(BUFB(bi) + row * 128 + ((g ^ (row & 7)) << 4));            \
      }                                                                                     \
      _Pragma("unroll") for (int m = 0; m < 2; ++m)                                         \
        _Pragma("unroll") for (int n = 0; n < 2; ++n)                                       \
          ACC[m][n] = __builtin_amdgcn_mfma_f32_16x16x32_bf16(af[m], bg[n], ACC[m][n], 0, 0, 0); \
    }                                                                                       \
  } while (0)

  // ---- triadic GEMM: K=2048, 32 steps of BK=64, 3-buffer counted-vmcnt ----
  int i0 = 0, i1 = 1, i2 = 2;
  STAGE_T(0, 0);
  STAGE_T(1, 1);
  for (int kt = 0; kt < 32; ++kt) {
    if (kt < 31) {
      asm volatile("s_waitcnt vmcnt(3)" ::: "memory");  // stage(kt) landed
    } else {
      asm volatile("s_waitcnt vmcnt(0)" ::: "memory");
    }
    __builtin_amdgcn_s_barrier();
    __builtin_amdgcn_sched_barrier(0);
    if (kt < 30) STAGE_T(kt + 2, i2);
    COMPUTE(acc1, i0);
    int tmp = i0; i0 = i1; i1 = i2; i2 = tmp;
  }
  __syncthreads();  // all waves done reading before buffer reuse

  // ---- hier GEMM: K=128 = 2 steps; both staged, one drain ----
  STAGE_H(0, 0);
  STAGE_H(1, 1);
  __syncthreads();  // compiler drains vmcnt before barrier
  COMPUTE(acc2, 0);
  COMPUTE(acc2, 1);
  __syncthreads();  // done reading before epilogue overwrites smem

  // ---- epilogue: stage ss/exp rows + cantor scalars in LDS ----
  float* ss_l = (float*)smem;            // [128][36] padded stride
  float* ex_l = (float*)(smem + 18432);  // [64][36]
  float* cm_l = (float*)(smem + 27648);  // [128]
  float* pr_l = (float*)(smem + 28160);  // [64]
  for (int i = t; i < 4096; i += 512) {
    int r = i >> 5, l = i & 31;
    ss_l[r * 36 + l] = ssb[(size_t)(brow + r) * 32 + l];
  }
  for (int i = t; i < 2048; i += 512) {
    int r = i >> 5, l = i & 31;
    ex_l[r * 36 + l] = expd[(size_t)(bcol + r) * 32 + l];
  }
  if (t < 128) cm_l[t] = cm[brow + t];
  if (t < 64) pr_l[t] = (bcol + t < C_DIM) ? proto[bcol + t] : 0.f;
  __syncthreads();

  const int col0 = wn * 32 + l15;
  const int row0 = wm * 32 + (gq << 2);
#pragma unroll
  for (int m = 0; m < 2; ++m) {
    float ssum[4][2];
#pragma unroll
    for (int j = 0; j < 4; ++j)
#pragma unroll
      for (int n = 0; n < 2; ++n) ssum[j][n] = 0.f;
#pragma unroll
    for (int l4 = 0; l4 < 32; l4 += 4) {
      f32x4 evv[2], sv[4];
#pragma unroll
      for (int n = 0; n < 2; ++n)
        evv[n] = *(const f32x4*)&ex_l[(col0 + n * 16) * 36 + l4];
#pragma unroll
      for (int j = 0; j < 4; ++j)
        sv[j] = *(const f32x4*)&ss_l[(row0 + m * 16 + j) * 36 + l4];
#pragma unroll
      for (int j = 0; j < 4; ++j)
#pragma unroll
        for (int n = 0; n < 2; ++n) {
          ssum[j][n] += fabsf(sv[j][0] - evv[n][0]) + fabsf(sv[j][1] - evv[n][1]) +
                        fabsf(sv[j][2] - evv[n][2]) + fabsf(sv[j][3] - evv[n][3]);
        }
    }
#pragma unroll
    for (int j = 0; j < 4; ++j) {
      int rloc = row0 + m * 16 + j;
      float cmv = cm_l[rloc];
#pragma unroll
      for (int n = 0; n < 2; ++n) {
        int cloc = col0 + n * 16;
        int cg = bcol + cloc;
        float tria = fminf(fmaxf(0.5f + 0.5f * acc1[m][n][j], EPS), 1.0f);
        float hier = fminf(fmaxf(0.5f + 0.25f * acc2[m][n][j], EPS), 1.0f);
        float sc = fminf(fmaxf(1.0f - ssum[j][n] * (1.0f / 31.0f), EPS), 1.0f);
        float d = cmv - pr_l[cloc];
        float cc = __expf(d * d * -10.0f) + 1e-8f;
        cc = fminf(fmaxf(cc, EPS), 1.0f);
        float p = tria * sc * cc * hier;
        if (cg < C_DIM)
          out[(size_t)(brow + rloc) * C_DIM + cg] = sqrtf(sqrtf(p));
      }
    }
  }
}

extern "C" void kernel_launch(void* const* d_in, const int* in_sizes, int n_in,
                              void* d_out, int out_size, void* d_ws, size_t ws_size,
                              hipStream_t stream) {
  (void)in_sizes; (void)n_in; (void)out_size; (void)ws_size;
  const float* pe = (const float*)d_in[0];     // B x L x F
  const float* cm = (const float*)d_in[1];     // B
  const float* sig = (const float*)d_in[2];    // C x L x F
  const float* proto = (const float*)d_in[3];  // C
  const float* lr = (const float*)d_in[4];     // C x L
  float* out = (float*)d_out;
  char* ws = (char*)d_ws;

  __hip_bfloat16* wsig = (__hip_bfloat16*)(ws);               // CP*2048*2 = 4 MiB
  __hip_bfloat16* pen = (__hip_bfloat16*)(ws + 4194304);      // B*2048*2 = 16 MiB
  __hip_bfloat16* elb = (__hip_bfloat16*)(ws + 20971520);     // B*128*2  = 1 MiB
  __hip_bfloat16* elc = (__hip_bfloat16*)(ws + 22020096);     // CP*128*2 = 256 KiB
  float* ssb = (float*)(ws + 22282240);                       // B*32*4   = 512 KiB
  float* expd = (float*)(ws + 22806528);                      // CP*32*4  = 128 KiB

  prep_all<<<CP + B_DIM, 64, 0, stream>>>(sig, lr, pe, wsig, expd, elc, pen, ssb, elb);
  dim3 grid(B_DIM / 128, CP / 64);
  basin_main<<<grid, 512, 0, stream>>>(pen, wsig, elb, elc, ssb, expd, cm, proto, out);
}

// Round 8
// 80.609 us; speedup vs baseline: 2.2536x; 2.1555x over previous
//
#include <hip/hip_runtime.h>
#include <hip/hip_bf16.h>

typedef float f32x4 __attribute__((ext_vector_type(4)));
typedef short bf16x8 __attribute__((ext_vector_type(8)));

#define B_DIM 4096
#define C_DIM 1000
#define CP 1024
#define K1 2048
#define EPS 1e-6f

__device__ __forceinline__ float wsum(float v) {
#pragma unroll
  for (int o = 32; o > 0; o >>= 1) v += __shfl_xor(v, o, 64);
  return v;
}
__device__ __forceinline__ float wmax(float v) {
#pragma unroll
  for (int o = 32; o > 0; o >>= 1) v = fmaxf(v, __shfl_xor(v, o, 64));
  return v;
}

__device__ __forceinline__ void load_lds16(const void* g, void* l) {
  __builtin_amdgcn_global_load_lds(
      (const __attribute__((address_space(1))) unsigned int*)g,
      (__attribute__((address_space(3))) unsigned int*)l, 16, 0, 0);
}

// ---- merged prep: blocks [0,CP) = per-class, [CP, CP+B_DIM) = per-b ----
__global__ void prep_all(const float* __restrict__ sig,
                         const float* __restrict__ lr,
                         const float* __restrict__ pe,
                         __hip_bfloat16* __restrict__ wsig,
                         float* __restrict__ expd,
                         __hip_bfloat16* __restrict__ elc,
                         __hip_bfloat16* __restrict__ pen,
                         float* __restrict__ ssb,
                         __hip_bfloat16* __restrict__ elb) {
  const int t = threadIdx.x;
  if (blockIdx.x < CP) {
    const int c = blockIdx.x;
    if (c >= C_DIM) {  // zero padding rows so the GEMM reads clean zeros
      for (int i = t; i < K1; i += 64) wsig[(size_t)c * K1 + i] = __float2bfloat16(0.f);
      if (t < 32) expd[c * 32 + t] = 0.f;
      elc[(size_t)c * 128 + t] = __float2bfloat16(0.f);
      elc[(size_t)c * 128 + 64 + t] = __float2bfloat16(0.f);
      return;
    }
    float lv = (t < 32) ? lr[c * 32 + t] : -3.0e38f;
    float mx = wmax(lv);
    float ev = (t < 32) ? expf(lv - mx) : 0.f;
    float sden = wsum(ev);
    float res = ev / sden;
    if (t < 31) {
      float d = lr[c * 32 + t] - lr[c * 32 + t + 1];
      expd[c * 32 + t] = 1.f / (1.f + expf(-d));
    } else if (t == 31) {
      expd[c * 32 + 31] = 0.f;
    }
    float es = 0.f, ls = 0.f;
    for (int l = 0; l < 32; ++l) {
      float s = sig[((size_t)c * 32 + l) * 64 + t];
      float nrm = fmaxf(sqrtf(wsum(s * s)), 1e-12f);
      float resl = __shfl(res, l, 64);
      wsig[((size_t)c * 32 + l) * 64 + t] = __float2bfloat16(s / nrm * resl);
      if (l < 16) es += s; else ls += s;
    }
    es *= (1.f / 16.f); ls *= (1.f / 16.f);
    float en = fmaxf(sqrtf(wsum(es * es)), 1e-12f);
    float ln2 = fmaxf(sqrtf(wsum(ls * ls)), 1e-12f);
    elc[(size_t)c * 128 + t] = __float2bfloat16(es / en);
    elc[(size_t)c * 128 + 64 + t] = __float2bfloat16(ls / ln2);
  } else {
    const int b = blockIdx.x - CP;
    float v[32];
#pragma unroll
    for (int l = 0; l < 32; ++l) v[l] = pe[((size_t)b * 32 + l) * 64 + t];
    float nrm[32];
#pragma unroll
    for (int l = 0; l < 32; ++l) nrm[l] = sqrtf(wsum(v[l] * v[l]));
#pragma unroll
    for (int l = 0; l < 32; ++l)
      pen[((size_t)b * 32 + l) * 64 + t] = __float2bfloat16(v[l] / fmaxf(nrm[l], 1e-12f));
#pragma unroll
    for (int l = 0; l < 31; ++l) {
      float dot = wsum(v[l] * v[l + 1]);
      float cosv = dot / (fmaxf(nrm[l], 1e-8f) * fmaxf(nrm[l + 1], 1e-8f));
      if (t == 0) ssb[(size_t)b * 32 + l] = (cosv + 1.0f) * 0.5f;
    }
    if (t == 0) ssb[(size_t)b * 32 + 31] = 0.0f;
    float es = 0.f, ls = 0.f;
#pragma unroll
    for (int l = 0; l < 16; ++l) es += v[l];
#pragma unroll
    for (int l = 16; l < 32; ++l) ls += v[l];
    es *= (1.f / 16.f); ls *= (1.f / 16.f);
    float en = fmaxf(sqrtf(wsum(es * es)), 1e-12f);
    float ln2 = fmaxf(sqrtf(wsum(ls * ls)), 1e-12f);
    elb[(size_t)b * 128 + t] = __float2bfloat16(es / en);
    elb[(size_t)b * 128 + 64 + t] = __float2bfloat16(ls / ln2);
  }
}

// ---- main fused: 128x64 tile, 8 waves (32x32 each), BK=64, 3-deep vmcnt ----
// launch_bounds(512,2): (512,4) forced a 64-VGPR cap -> massive scratch spills
// (R6/R7: FETCH/WRITE 8-15x amplified, 156us). LDS 72KB already caps at
// 2 blocks/CU = 4 waves/SIMD; don't constrain VGPRs below need.
__global__ __launch_bounds__(512, 2)
void basin_main(const __hip_bfloat16* __restrict__ pen,
                const __hip_bfloat16* __restrict__ wsig,
                const __hip_bfloat16* __restrict__ elb,
                const __hip_bfloat16* __restrict__ elc,
                const float* __restrict__ ssb,
                const float* __restrict__ expd,
                const float* __restrict__ cm,
                const float* __restrict__ proto,
                float* __restrict__ out) {
  __shared__ __align__(16) char smem[73728];  // 3 x (A 16KB + B 8KB)
  const int t = threadIdx.x;
  const int lane = t & 63;
  const int w = t >> 6;                // 0..7
  const int wm = w >> 1, wn = w & 1;   // 4M x 2N waves, each 32x32
  const int brow = blockIdx.x * 128;
  const int bcol = blockIdx.y * 64;
  // staging: 8 threads per 128B row; granule-XOR swizzle (both sides, row&7)
  const int srow = t >> 3;                          // 0..63
  const int selem = (((t & 7) ^ (srow & 7)) << 3);  // pre-swizzled source elem
  const int l15 = lane & 15;
  const int gq = lane >> 4;                         // quarter 0..3

  f32x4 acc1[2][2] = {};
  f32x4 acc2[2][2] = {};

#define BUFA(bi) (smem + (bi) * 24576)
#define BUFB(bi) (smem + (bi) * 24576 + 16384)

#define STAGE_T(kt, bi)                                                                     \
  do {                                                                                      \
    load_lds16(pen + (size_t)(brow + srow) * K1 + (kt) * 64 + selem, BUFA(bi) + t * 16);    \
    load_lds16(pen + (size_t)(brow + 64 + srow) * K1 + (kt) * 64 + selem,                   \
               BUFA(bi) + 8192 + t * 16);                                                   \
    load_lds16(wsig + (size_t)(bcol + srow) * K1 + (kt) * 64 + selem, BUFB(bi) + t * 16);   \
  } while (0)

#define STAGE_H(kt, bi)                                                                     \
  do {                                                                                      \
    load_lds16(elb + (size_t)(brow + srow) * 128 + (kt) * 64 + selem, BUFA(bi) + t * 16);   \
    load_lds16(elb + (size_t)(brow + 64 + srow) * 128 + (kt) * 64 + selem,                  \
               BUFA(bi) + 8192 + t * 16);                                                   \
    load_lds16(elc + (size_t)(bcol + srow) * 128 + (kt) * 64 + selem, BUFB(bi) + t * 16);   \
  } while (0)

// per K-step: 2 sub-steps (kk), 8 ds_read_b128, 8 MFMA
#define COMPUTE(ACC, bi)                                                                    \
  do {                                                                                      \
    _Pragma("unroll") for (int kk = 0; kk < 2; ++kk) {                                      \
      bf16x8 af[2], bg[2];                                                                  \
      _Pragma("unroll") for (int m = 0; m < 2; ++m) {                                       \
        int row = wm * 32 + m * 16 + l15;                                                   \
        int g = kk * 4 + gq;                                                                \
        af[m] = *(const bf16x8*)(BUFA(bi) + row * 128 + ((g ^ (row & 7)) << 4));            \
      }                                                                                     \
      _Pragma("unroll") for (int n = 0; n < 2; ++n) {                                       \
        int row = wn * 32 + n * 16 + l15;                                                   \
        int g = kk * 4 + gq;                                                                \
        bg[n] = *(const bf16x8*)(BUFB(bi) + row * 128 + ((g ^ (row & 7)) << 4));            \
      }                                                                                     \
      _Pragma("unroll") for (int m = 0; m < 2; ++m)                                         \
        _Pragma("unroll") for (int n = 0; n < 2; ++n)                                       \
          ACC[m][n] = __builtin_amdgcn_mfma_f32_16x16x32_bf16(af[m], bg[n], ACC[m][n], 0, 0, 0); \
    }                                                                                       \
  } while (0)

  // ---- triadic GEMM: K=2048, 32 steps of BK=64, 3-buffer counted-vmcnt ----
  int i0 = 0, i1 = 1, i2 = 2;
  STAGE_T(0, 0);
  STAGE_T(1, 1);
  for (int kt = 0; kt < 32; ++kt) {
    if (kt < 31) {
      asm volatile("s_waitcnt vmcnt(3)" ::: "memory");  // stage(kt) landed
    } else {
      asm volatile("s_waitcnt vmcnt(0)" ::: "memory");
    }
    __builtin_amdgcn_s_barrier();
    __builtin_amdgcn_sched_barrier(0);
    if (kt < 30) STAGE_T(kt + 2, i2);
    COMPUTE(acc1, i0);
    int tmp = i0; i0 = i1; i1 = i2; i2 = tmp;
  }
  __syncthreads();  // all waves done reading before buffer reuse

  // ---- hier GEMM: K=128 = 2 steps; both staged, one drain ----
  STAGE_H(0, 0);
  STAGE_H(1, 1);
  __syncthreads();  // compiler drains vmcnt before barrier
  COMPUTE(acc2, 0);
  COMPUTE(acc2, 1);
  __syncthreads();  // done reading before epilogue overwrites smem

  // ---- epilogue: stage ss/exp rows + cantor scalars in LDS ----
  float* ss_l = (float*)smem;            // [128][36] padded stride
  float* ex_l = (float*)(smem + 18432);  // [64][36]
  float* cm_l = (float*)(smem + 27648);  // [128]
  float* pr_l = (float*)(smem + 28160);  // [64]
  for (int i = t; i < 4096; i += 512) {
    int r = i >> 5, l = i & 31;
    ss_l[r * 36 + l] = ssb[(size_t)(brow + r) * 32 + l];
  }
  for (int i = t; i < 2048; i += 512) {
    int r = i >> 5, l = i & 31;
    ex_l[r * 36 + l] = expd[(size_t)(bcol + r) * 32 + l];
  }
  if (t < 128) cm_l[t] = cm[brow + t];
  if (t < 64) pr_l[t] = (bcol + t < C_DIM) ? proto[bcol + t] : 0.f;
  __syncthreads();

  const int col0 = wn * 32 + l15;
  const int row0 = wm * 32 + (gq << 2);
#pragma unroll
  for (int m = 0; m < 2; ++m) {
    float ssum[4][2];
#pragma unroll
    for (int j = 0; j < 4; ++j)
#pragma unroll
      for (int n = 0; n < 2; ++n) ssum[j][n] = 0.f;
#pragma unroll
    for (int l4 = 0; l4 < 32; l4 += 4) {
      f32x4 evv[2], sv[4];
#pragma unroll
      for (int n = 0; n < 2; ++n)
        evv[n] = *(const f32x4*)&ex_l[(col0 + n * 16) * 36 + l4];
#pragma unroll
      for (int j = 0; j < 4; ++j)
        sv[j] = *(const f32x4*)&ss_l[(row0 + m * 16 + j) * 36 + l4];
#pragma unroll
      for (int j = 0; j < 4; ++j)
#pragma unroll
        for (int n = 0; n < 2; ++n) {
          ssum[j][n] += fabsf(sv[j][0] - evv[n][0]) + fabsf(sv[j][1] - evv[n][1]) +
                        fabsf(sv[j][2] - evv[n][2]) + fabsf(sv[j][3] - evv[n][3]);
        }
    }
#pragma unroll
    for (int j = 0; j < 4; ++j) {
      int rloc = row0 + m * 16 + j;
      float cmv = cm_l[rloc];
#pragma unroll
      for (int n = 0; n < 2; ++n) {
        int cloc = col0 + n * 16;
        int cg = bcol + cloc;
        float tria = fminf(fmaxf(0.5f + 0.5f * acc1[m][n][j], EPS), 1.0f);
        float hier = fminf(fmaxf(0.5f + 0.25f * acc2[m][n][j], EPS), 1.0f);
        float sc = fminf(fmaxf(1.0f - ssum[j][n] * (1.0f / 31.0f), EPS), 1.0f);
        float d = cmv - pr_l[cloc];
        float cc = __expf(d * d * -10.0f) + 1e-8f;
        cc = fminf(fmaxf(cc, EPS), 1.0f);
        float p = tria * sc * cc * hier;
        if (cg < C_DIM)
          out[(size_t)(brow + rloc) * C_DIM + cg] = sqrtf(sqrtf(p));
      }
    }
  }
}

extern "C" void kernel_launch(void* const* d_in, const int* in_sizes, int n_in,
                              void* d_out, int out_size, void* d_ws, size_t ws_size,
                              hipStream_t stream) {
  (void)in_sizes; (void)n_in; (void)out_size; (void)ws_size;
  const float* pe = (const float*)d_in[0];     // B x L x F
  const float* cm = (const float*)d_in[1];     // B
  const float* sig = (const float*)d_in[2];    // C x L x F
  const float* proto = (const float*)d_in[3];  // C
  const float* lr = (const float*)d_in[4];     // C x L
  float* out = (float*)d_out;
  char* ws = (char*)d_ws;

  __hip_bfloat16* wsig = (__hip_bfloat16*)(ws);               // CP*2048*2 = 4 MiB
  __hip_bfloat16* pen = (__hip_bfloat16*)(ws + 4194304);      // B*2048*2 = 16 MiB
  __hip_bfloat16* elb = (__hip_bfloat16*)(ws + 20971520);     // B*128*2  = 1 MiB
  __hip_bfloat16* elc = (__hip_bfloat16*)(ws + 22020096);     // CP*128*2 = 256 KiB
  float* ssb = (float*)(ws + 22282240);                       // B*32*4   = 512 KiB
  float* expd = (float*)(ws + 22806528);                      // CP*32*4  = 128 KiB

  prep_all<<<CP + B_DIM, 64, 0, stream>>>(sig, lr, pe, wsig, expd, elc, pen, ssb, elb);
  dim3 grid(B_DIM / 128, CP / 64);
  basin_main<<<grid, 512, 0, stream>>>(pen, wsig, elb, elc, ssb, expd, cm, proto, out);
}